// Round 6
// baseline (881.045 us; speedup 1.0000x reference)
//
#include <hip/hip_runtime.h>
#include <hip/hip_bf16.h>
#include <stdint.h>

// B=512 L=32 E=2048 H=32 D=64 ; M = B*L = 16384 ; K = 2048 ; Nqkv = 6144
typedef __bf16 bf16x8 __attribute__((ext_vector_type(8)));
typedef float f32x4 __attribute__((ext_vector_type(4)));
typedef unsigned short u16x8 __attribute__((ext_vector_type(8)));
typedef unsigned short u16x4 __attribute__((ext_vector_type(4)));

#define G_AS __attribute__((address_space(1)))
#define L_AS __attribute__((address_space(3)))

__device__ __forceinline__ void gload_lds16(const void* g, void* l) {
  __builtin_amdgcn_global_load_lds((G_AS void*)g, (L_AS void*)l, 16, 0, 0);
}

__device__ __forceinline__ float b2f(unsigned short u) {
  union { float f; unsigned int i; } cv;
  cv.i = ((unsigned int)u) << 16;
  return cv.f;
}

__device__ __forceinline__ unsigned short f2b(float f) {
  unsigned int u = __float_as_uint(f);
  unsigned int r = u + 0x7FFFu + ((u >> 16) & 1u);  // RNE (inputs are non-NaN)
  return (unsigned short)(r >> 16);
}

// ---------------- cast / pack kernels ----------------

__global__ void k_cast_f32_bf16(const float* __restrict__ src,
                                unsigned short* __restrict__ dst, int n4) {
  int i = blockIdx.x * blockDim.x + threadIdx.x;
  if (i >= n4) return;
  float4 v = reinterpret_cast<const float4*>(src)[i];
  u16x4 o;
  o[0] = f2b(v.x); o[1] = f2b(v.y); o[2] = f2b(v.z); o[3] = f2b(v.w);
  reinterpret_cast<u16x4*>(dst)[i] = o;
}

// wqkvb rows: [0,2048)=wq, [2048,4096)=wk*0.125 (folds softmax scale), [4096,6144)=wv
__global__ void k_build_wqkv(const float* __restrict__ wq, const float* __restrict__ wk,
                             const float* __restrict__ wv, unsigned short* __restrict__ dst) {
  int i = blockIdx.x * blockDim.x + threadIdx.x;  // 6144*2048/4 = 3145728 threads
  if (i >= 3145728) return;
  int e = i << 2;
  int row = e >> 11;
  int col = e & 2047;
  const float* src; float sc = 1.0f;
  if (row < 2048) { src = wq + ((size_t)row << 11); }
  else if (row < 4096) { src = wk + ((size_t)(row - 2048) << 11); sc = 0.125f; }
  else { src = wv + ((size_t)(row - 4096) << 11); }
  float4 v = *reinterpret_cast<const float4*>(src + col);
  u16x4 o;
  o[0] = f2b(v.x * sc); o[1] = f2b(v.y * sc); o[2] = f2b(v.z * sc); o[3] = f2b(v.w * sc);
  *reinterpret_cast<u16x4*>(dst + e) = o;
}

__global__ void k_build_bqkv(const float* __restrict__ bq, const float* __restrict__ bk,
                             const float* __restrict__ bv, float* __restrict__ dst) {
  int i = blockIdx.x * blockDim.x + threadIdx.x;
  if (i >= 6144) return;
  float v;
  if (i < 2048) v = bq[i];
  else if (i < 4096) v = bk[i - 2048] * 0.125f;
  else v = bv[i - 4096];
  dst[i] = v;
}

// relb[h][j][d] = rpe[h - j + 31][d]   (faithful to the reference's H==L broadcast quirk)
__global__ void k_build_rel(const float* __restrict__ rpe, unsigned short* __restrict__ dst) {
  int i = blockIdx.x * blockDim.x + threadIdx.x;  // 32*32*16 = 16384
  if (i >= 16384) return;
  int h = i >> 9;
  int j = (i >> 4) & 31;
  int d = (i & 15) << 2;
  const float* s = rpe + (size_t)(h - j + 31) * 64 + d;
  float4 v = *reinterpret_cast<const float4*>(s);
  u16x4 o;
  o[0] = f2b(v.x); o[1] = f2b(v.y); o[2] = f2b(v.z); o[3] = f2b(v.w);
  *reinterpret_cast<u16x4*>(dst + ((size_t)i << 2)) = o;
}

// ---------------- GEMM: C[M][N] = A[M][K] * B[N][K]^T + bias[N] ----------------
// m201-geometry: 256x256 tile, BK=64, 2 K-tiles/iter, 8 phases/iter, 8 waves (2Mx4N),
// 512 threads, double-buffered LDS (128 KiB). Per phase: {ds_read 12/8/4/0 into held
// register frags + 1 half-tile stage (2 gload_lds) + 16 MFMA}. vmcnt(4) at ph0/ph4
// only (peeled tail: vmcnt(0) once). 8 barriers per K=128.
//
// LDS chunk layout per (buf, matrix): 16B chunk (row, slot) at
//   phys = (row>>3)*64 + slot*8 + (row&7),  slot = k/8 (0..7), rows 0..255
// -> 16-lane frag read sweeps all 32 banks 2x (free). Staging: linear dest chunk,
// global source permuted: row = ((c>>6)<<3)|(c&7), col8 = (c>>3)&7 (inverse verified).
//
// Hazard ledger (iter i computes T0=2i in buf0 ph0-3, T1=2i+1 in buf1 ph4-7):
//  stage schedule: ph0 B(T1)h0->Bs1, ph1 B(T1)h1, ph2 A(T0+2)h0->As0, ph3 A(T0+2)h1,
//                  ph4 B(T0+2)h0->Bs0, ph5 B(T0+2)h1, ph6 A(T1+2)h0->As1, ph7 A(T1+2)h1
//  RAW: ph0 vmcnt(4) leaves {A(T1) 4 loads} -> A(T0),B(T0) landed; barrier -> block-wide.
//       ph4 vmcnt(4) leaves {ph2,ph3 A 4 loads} -> B(T1) landed.
//  WAR: region last read at phase d drains before MFMA_d < postB_d; stage at phase
//       s>=d+1 issues after postB_{s-1} >= postB_d.  (As0: d=1,s=2; Bs0: d=2,s=4;
//       As1: d=5,s=6; Bs1: d=prev6,s=0 after ph0 pre-barrier > prev postB_6.)

#define PB asm volatile("s_barrier" ::: "memory")

#define STG(mat, buf, T, h)                                                              \
  do {                                                                                   \
    gload_lds16(ag##mat + (size_t)((h) * 128) * K + (T) * 64,                            \
                &mat##s[buf][(h) * 8192 + ld0]);                                         \
    gload_lds16(ag##mat + (size_t)((h) * 128 + 64) * K + (T) * 64,                       \
                &mat##s[buf][(h) * 8192 + ld0 + 4096]);                                  \
  } while (0)

#define RD_A03(p)                                                                        \
  do {                                                                                   \
    _Pragma("unroll") for (int mm = 0; mm < 4; ++mm)                                     \
    _Pragma("unroll") for (int ks = 0; ks < 2; ++ks)                                     \
      a03[mm][ks] = *reinterpret_cast<const bf16x8*>((p) + aBase + mm * 1024 + ks * 256);\
  } while (0)
#define RD_A47(p)                                                                        \
  do {                                                                                   \
    _Pragma("unroll") for (int mm = 0; mm < 4; ++mm)                                     \
    _Pragma("unroll") for (int ks = 0; ks < 2; ++ks)                                     \
      a47[mm][ks] = *reinterpret_cast<const bf16x8*>((p) + aBase + (mm + 4) * 1024 + ks * 256);\
  } while (0)
#define RD_B01(p)                                                                        \
  do {                                                                                   \
    _Pragma("unroll") for (int nn = 0; nn < 2; ++nn)                                     \
    _Pragma("unroll") for (int ks = 0; ks < 2; ++ks)                                     \
      b01[nn][ks] = *reinterpret_cast<const bf16x8*>((p) + bBase + nn * 1024 + ks * 256);\
  } while (0)
#define RD_B23(p)                                                                        \
  do {                                                                                   \
    _Pragma("unroll") for (int nn = 0; nn < 2; ++nn)                                     \
    _Pragma("unroll") for (int ks = 0; ks < 2; ++ks)                                     \
      b23[nn][ks] = *reinterpret_cast<const bf16x8*>((p) + bBase + (nn + 2) * 1024 + ks * 256);\
  } while (0)

#define MF(AF, BF, mlo, nlo)                                                             \
  do {                                                                                   \
    __builtin_amdgcn_s_setprio(1);                                                       \
    _Pragma("unroll") for (int ks = 0; ks < 2; ++ks)                                     \
    _Pragma("unroll") for (int mm = 0; mm < 4; ++mm)                                     \
    _Pragma("unroll") for (int nn = 0; nn < 2; ++nn)                                     \
      acc[(mlo) + mm][(nlo) + nn] = __builtin_amdgcn_mfma_f32_16x16x32_bf16(             \
          AF[mm][ks], BF[nn][ks], acc[(mlo) + mm][(nlo) + nn], 0, 0, 0);                 \
    __builtin_amdgcn_s_setprio(0);                                                       \
  } while (0)

#define ITER(T0, T1, ST, VMA, VMB)                                                       \
  {                                                                                      \
    /* ph0 */                                                                            \
    asm volatile(VMA ::: "memory");                                                      \
    PB;                                                                                  \
    RD_A03(a0p); RD_B01(b0p);                                                            \
    STG(B, 1, (T1), 0);                                                                  \
    MF(a03, b01, 0, 0);                                                                  \
    PB;                                                                                  \
    /* ph1 */                                                                            \
    RD_A47(a0p);                                                                         \
    STG(B, 1, (T1), 1);                                                                  \
    MF(a47, b01, 4, 0);                                                                  \
    PB;                                                                                  \
    /* ph2 */                                                                            \
    RD_B23(b0p);                                                                         \
    if (ST) STG(A, 0, (T0) + 2, 0);                                                      \
    MF(a03, b23, 0, 2);                                                                  \
    PB;                                                                                  \
    /* ph3 (no closing barrier: subsumed by ph4 pre-barrier) */                          \
    if (ST) STG(A, 0, (T0) + 2, 1);                                                      \
    MF(a47, b23, 4, 2);                                                                  \
    /* ph4 */                                                                            \
    asm volatile(VMB ::: "memory");                                                      \
    PB;                                                                                  \
    RD_A03(a1p); RD_B01(b1p);                                                            \
    if (ST) STG(B, 0, (T0) + 2, 0);                                                      \
    MF(a03, b01, 0, 0);                                                                  \
    PB;                                                                                  \
    /* ph5 */                                                                            \
    RD_A47(a1p);                                                                         \
    if (ST) STG(B, 0, (T0) + 2, 1);                                                      \
    MF(a47, b01, 4, 0);                                                                  \
    PB;                                                                                  \
    /* ph6 */                                                                            \
    RD_B23(b1p);                                                                         \
    if (ST) STG(A, 1, (T1) + 2, 0);                                                      \
    MF(a03, b23, 0, 2);                                                                  \
    PB;                                                                                  \
    /* ph7 (no closing barrier: subsumed by next ph0 pre-barrier) */                     \
    if (ST) STG(A, 1, (T1) + 2, 1);                                                      \
    MF(a47, b23, 4, 2);                                                                  \
  }

template <int OUT_F32>
__global__ __launch_bounds__(512, 2)
void k_gemm256(const unsigned short* __restrict__ A,
               const unsigned short* __restrict__ B,
               const float* __restrict__ bias,
               void* __restrict__ Cptr,
               int M, int N, int K)
{
  __shared__ __align__(16) unsigned short As[2][16384];
  __shared__ __align__(16) unsigned short Bs[2][16384];

  // bijective XCD swizzle, bm-major
  const int nbn = N >> 8;
  const int cpx = gridDim.x >> 3;
  const int orig = blockIdx.x;
  const int wg = (orig & 7) * cpx + (orig >> 3);
  const int bm = wg / nbn;
  const int bn = wg % nbn;

  const int tid = threadIdx.x;
  const int lane = tid & 63;
  const int wid = tid >> 6;
  const int wr = wid >> 2;   // 0..1  (m-half)
  const int wc = wid & 3;    // 0..3  (64-col strip)

  // staging: chunk c=tid -> row r0, col cb; chunk c=tid+512 -> row r0+64
  const int r0 = ((tid >> 6) << 3) + (tid & 7);   // 0..63
  const int cb = ((tid >> 3) & 7) << 3;           // 0..56
  const unsigned short* agA = A + (size_t)(bm * 256 + r0) * K + cb;
  const unsigned short* agB = B + (size_t)(bn * 256 + r0) * K + cb;
  const int ld0 = tid * 8;

  // fragment read bases (ushort index in one 16384-ushort buffer)
  const int fr = lane & 15;
  const int q  = lane >> 4;
  const int aBase = ((wr * 16 + (fr >> 3)) * 64 + q * 8 + (fr & 7)) * 8;  // +m*1024 +ks*256
  const int bBase = ((wc * 8  + (fr >> 3)) * 64 + q * 8 + (fr & 7)) * 8;  // +n*1024 +ks*256

  const unsigned short* a0p = &As[0][0];
  const unsigned short* a1p = &As[1][0];
  const unsigned short* b0p = &Bs[0][0];
  const unsigned short* b1p = &Bs[1][0];

  f32x4 acc[8][4] = {};
  bf16x8 a03[4][2], a47[4][2], b01[2][2], b23[2][2];

  // prologue: A(0), B(0), A(1)  (12 loads; B(1) staged in iter0 ph0/ph1)
  STG(A, 0, 0, 0); STG(A, 0, 0, 1);
  STG(B, 0, 0, 0); STG(B, 0, 0, 1);
  STG(A, 1, 1, 0); STG(A, 1, 1, 1);

  // K=2048 -> 32 K-tiles of 64 -> 16 iters; last peeled (no t+2/t+3 staging)
  for (int i = 0; i < 15; ++i) {
    const int T0 = 2 * i;
    const int T1 = 2 * i + 1;
    ITER(T0, T1, true, "s_waitcnt vmcnt(4)", "s_waitcnt vmcnt(4)")
  }
  ITER(30, 31, false, "s_waitcnt vmcnt(4)", "s_waitcnt vmcnt(0)")

  // epilogue: C/D layout col = lane&15, row = (lane>>4)*4 + reg
  const int rBase = bm * 256 + wr * 128 + (q << 2);
  const int cBase = bn * 256 + wc * 64 + fr;
#pragma unroll
  for (int n = 0; n < 4; ++n) {
    const int col = cBase + n * 16;
    const float bv = bias[col];
#pragma unroll
    for (int m = 0; m < 8; ++m) {
      const int row = rBase + m * 16;
#pragma unroll
      for (int r = 0; r < 4; ++r) {
        float v = acc[m][n][r] + bv;
        if (OUT_F32) {
          reinterpret_cast<float*>(Cptr)[(size_t)(row + r) * N + col] = v;
        } else {
          reinterpret_cast<unsigned short*>(Cptr)[(size_t)(row + r) * N + col] = f2b(v);
        }
      }
    }
  }
}

// ---------------- attention: one block (256 thr) per (b,h) ----------------

__global__ __launch_bounds__(256)
void k_attn(const unsigned short* __restrict__ qkv,
            const unsigned short* __restrict__ relb,
            unsigned short* __restrict__ ctx)
{
  __shared__ float qL[32][68];
  __shared__ float krL[32][68];
  __shared__ float vL[32][68];
  __shared__ float SL[32][33];

  const int bh = blockIdx.x;
  const int b = bh >> 5;
  const int h = bh & 31;
  const int t = threadIdx.x;
  const int r = t >> 3;           // row 0..31
  const int d0 = (t & 7) << 3;    // d 0..56 step 8

  const unsigned short* base = qkv + (size_t)(b * 32 + r) * 6144 + h * 64 + d0;
  u16x8 uq = *reinterpret_cast<const u16x8*>(base);
  u16x8 uk = *reinterpret_cast<const u16x8*>(base + 2048);
  u16x8 uv = *reinterpret_cast<const u16x8*>(base + 4096);
  u16x8 ur = *reinterpret_cast<const u16x8*>(relb + (((size_t)(h * 32 + r)) << 6) + d0);

  float fq[8], fkr[8], fv[8];
#pragma unroll
  for (int c = 0; c < 8; ++c) {
    fq[c] = b2f(uq[c]);
    fkr[c] = b2f(uk[c]) + b2f(ur[c]);
    fv[c] = b2f(uv[c]);
  }
  *reinterpret_cast<float4*>(&qL[r][d0])      = make_float4(fq[0], fq[1], fq[2], fq[3]);
  *reinterpret_cast<float4*>(&qL[r][d0 + 4])  = make_float4(fq[4], fq[5], fq[6], fq[7]);
  *reinterpret_cast<float4*>(&krL[r][d0])     = make_float4(fkr[0], fkr[1], fkr[2], fkr[3]);
  *reinterpret_cast<float4*>(&krL[r][d0 + 4]) = make_float4(fkr[4], fkr[5], fkr[6], fkr[7]);
  *reinterpret_cast<float4*>(&vL[r][d0])      = make_float4(fv[0], fv[1], fv[2], fv[3]);
  *reinterpret_cast<float4*>(&vL[r][d0 + 4])  = make_float4(fv[4], fv[5], fv[6], fv[7]);
  __syncthreads();

  const int i = r;
  const int j0 = (t & 7) << 2;   // 4 score cols per thread
  float s0 = 0.f, s1 = 0.f, s2 = 0.f, s3 = 0.f;
#pragma unroll
  for (int d = 0; d < 64; d += 4) {
    float4 qv = *reinterpret_cast<const float4*>(&qL[i][d]);
    float4 k0 = *reinterpret_cast<const float4*>(&krL[j0 + 0][d]);
    float4 k1 = *reinterpret_cast<const float4*>(&krL[j0 + 1][d]);
    float4 k2 = *reinterpret_cast<const float4*>(&krL[j0 + 2][d]);
    float4 k3 = *reinterpret_cast<const float4*>(&krL[j0 + 3][d]);
    s0 += qv.x * k0.x + qv.y * k0.y + qv.z * k0.z + qv.w * k0.w;
    s1 += qv.x * k1.x + qv.y * k1.y + qv.z * k1.z + qv.w * k1.w;
    s2 += qv.x * k2.x + qv.y * k2.y + qv.z * k2.z + qv.w * k2.w;
    s3 += qv.x * k3.x + qv.y * k3.y + qv.z * k3.z + qv.w * k3.w;
  }
  SL[i][j0 + 0] = s0; SL[i][j0 + 1] = s1; SL[i][j0 + 2] = s2; SL[i][j0 + 3] = s3;
  __syncthreads();

  float m = SL[i][0];
#pragma unroll
  for (int jj = 1; jj < 32; ++jj) m = fmaxf(m, SL[i][jj]);
  __syncthreads();  // all max reads done before P overwrites S

  float p0 = __expf(s0 - m), p1 = __expf(s1 - m), p2 = __expf(s2 - m), p3 = __expf(s3 - m);
  SL[i][j0 + 0] = p0; SL[i][j0 + 1] = p1; SL[i][j0 + 2] = p2; SL[i][j0 + 3] = p3;
  __syncthreads();

  float den = 0.f;
#pragma unroll
  for (int jj = 0; jj < 32; ++jj) den += SL[i][jj];
  const float inv = 1.0f / den;

  float o[8] = {0.f, 0.f, 0.f, 0.f, 0.f, 0.f, 0.f, 0.f};
#pragma unroll
  for (int jj = 0; jj < 32; ++jj) {
    float pj = SL[i][jj];
    float4 v0 = *reinterpret_cast<const float4*>(&vL[jj][d0]);
    float4 v1 = *reinterpret_cast<const float4*>(&vL[jj][d0 + 4]);
    o[0] += pj * v0.x; o[1] += pj * v0.y; o[2] += pj * v0.z; o[3] += pj * v0.w;
    o[4] += pj * v1.x; o[5] += pj * v1.y; o[6] += pj * v1.z; o[7] += pj * v1.w;
  }
  u16x8 ov;
#pragma unroll
  for (int c = 0; c < 8; ++c) ov[c] = f2b(o[c] * inv);
  *reinterpret_cast<u16x8*>(ctx + (size_t)(b * 32 + i) * 2048 + h * 64 + d0) = ov;
}

// ---------------- launch ----------------

extern "C" void kernel_launch(void* const* d_in, const int* in_sizes, int n_in,
                              void* d_out, int out_size, void* d_ws, size_t ws_size,
                              hipStream_t stream) {
  const float* x   = (const float*)d_in[0];
  const float* wq  = (const float*)d_in[1];
  const float* bq  = (const float*)d_in[2];
  const float* wk  = (const float*)d_in[3];
  const float* bk  = (const float*)d_in[4];
  const float* wv  = (const float*)d_in[5];
  const float* bv  = (const float*)d_in[6];
  const float* wo  = (const float*)d_in[7];
  const float* bo  = (const float*)d_in[8];
  const float* rpe = (const float*)d_in[9];

  char* ws = (char*)d_ws;
  unsigned short* xb    = (unsigned short*)(ws);
  unsigned short* wqkvb = (unsigned short*)(ws + 67108864);
  unsigned short* wob   = (unsigned short*)(ws + 67108864 + 25165824);
  unsigned short* qkvb  = (unsigned short*)(ws + 67108864 + 25165824 + 8388608);
  float*          bqkv  = (float*)(ws + 67108864 + 25165824 + 8388608 + 201326592);
  unsigned short* relb  = (unsigned short*)(ws + 67108864 + 25165824 + 8388608 + 201326592 + 24576);

  k_cast_f32_bf16<<<32768, 256, 0, stream>>>(x, xb, 8388608);          // 16384*2048/4
  k_build_wqkv<<<12288, 256, 0, stream>>>(wq, wk, wv, wqkvb);
  k_cast_f32_bf16<<<4096, 256, 0, stream>>>(wo, wob, 1048576);         // 2048*2048/4
  k_build_bqkv<<<24, 256, 0, stream>>>(bq, bk, bv, bqkv);
  k_build_rel<<<64, 256, 0, stream>>>(rpe, relb);

  // QKV projection: [16384][6144] = xb * wqkvb^T + bqkv  (bf16 out); grid 64x24=1536 (%8==0)
  k_gemm256<0><<<(16384 / 256) * (6144 / 256), 512, 0, stream>>>(
      xb, wqkvb, bqkv, qkvb, 16384, 6144, 2048);

  // attention -> ctx (reuses xb buffer)
  k_attn<<<16384, 256, 0, stream>>>(qkvb, relb, xb);

  // output projection: [16384][2048] = ctx * wob^T + bo  (fp32 out); grid 64x8=512 (%8==0)
  k_gemm256<1><<<(16384 / 256) * (2048 / 256), 512, 0, stream>>>(
      xb, wob, bo, (float*)d_out, 16384, 2048, 2048);
}